// Round 11
// baseline (58.062 us; speedup 1.0000x reference)
//
#include <hip/hip_runtime.h>

// Problem constants
#define LIN   4096
#define NCH   8
#define NBS   16
#define THREADS 256
#define NBLK  512           // 16 b x 32 pb; 128 positions/block (R5 geometry, 2 blocks/CU)
#define W     4             // windows per thread
// d_ws layout (bytes):
//  [0..3]     cnt (uint) — zeroed by in-graph hipMemsetAsync each replay
//  [256..]    float slots[NBLK][4] — per-block relu'd maxima, plain stores (always fully
//             written before the counter fires; R4-validated protocol)

// ---------------- register statevector sim (validated R0/R3/R5/R7/R8/R10: absmax 0.0) ----------------
template<int BIT>
__device__ __forceinline__ void apply_rx(float sr[16], float si[16], float c, float s) {
#pragma unroll
  for (int k = 0; k < 16; ++k) {
    if ((k & BIT) == 0) {
      const int a = k, b = k | BIT;
      const float ar = sr[a], ai = si[a], br = sr[b], bi = si[b];
      sr[a] = c * ar + s * bi;
      si[a] = c * ai - s * br;
      sr[b] = c * br + s * ai;
      si[b] = c * bi - s * ar;
    }
  }
}

template<int BIT>
__device__ __forceinline__ void apply_ry(float sr[16], float si[16], float c, float s) {
#pragma unroll
  for (int k = 0; k < 16; ++k) {
    if ((k & BIT) == 0) {
      const int a = k, b = k | BIT;
      const float ar = sr[a], ai = si[a], br = sr[b], bi = si[b];
      sr[a] = c * ar - s * br;
      si[a] = c * ai - s * bi;
      sr[b] = s * ar + c * br;
      si[b] = s * ai + c * bi;
    }
  }
}

template<int CBIT, int TBIT>
__device__ __forceinline__ void apply_cnot(float sr[16], float si[16]) {
#pragma unroll
  for (int k = 0; k < 16; ++k) {
    if ((k & CBIT) != 0 && (k & TBIT) == 0) {
      const int a = k, b = k | TBIT;
      float t;
      t = sr[a]; sr[a] = sr[b]; sr[b] = t;
      t = si[a]; si[a] = si[b]; si[b] = t;
    }
  }
}

__device__ __forceinline__ void basic_layer(float sr[16], float si[16],
                                            const float c[4], const float s[4]) {
  apply_rx<8>(sr, si, c[0], s[0]);
  apply_rx<4>(sr, si, c[1], s[1]);
  apply_rx<2>(sr, si, c[2], s[2]);
  apply_rx<1>(sr, si, c[3], s[3]);
  apply_cnot<8, 4>(sr, si);
  apply_cnot<4, 2>(sr, si);
  apply_cnot<2, 1>(sr, si);
  apply_cnot<1, 8>(sr, si);
}

__device__ void sim_circuit(const float* __restrict__ weights, float w0, float w1, float ev[4]) {
  float wc[3][4], wsn[3][4];
#pragma unroll
  for (int l = 0; l < 3; ++l)
#pragma unroll
    for (int q = 0; q < 4; ++q)
      __sincosf(weights[l * 4 + q] * 0.5f, &wsn[l][q], &wc[l][q]);

  float c0, s0, c1, s1;
  __sincosf(w0 * 0.5f, &s0, &c0);
  __sincosf(w1 * 0.5f, &s1, &c1);

  float sr[16], si[16];
#pragma unroll
  for (int k = 0; k < 16; ++k) { sr[k] = 0.0f; si[k] = 0.0f; }
  sr[0] = 1.0f;

  basic_layer(sr, si, wc[0], wsn[0]);
  apply_ry<8>(sr, si, c0, s0);
  apply_ry<4>(sr, si, c1, s1);
  apply_ry<2>(sr, si, c0, s0);
  apply_ry<1>(sr, si, c1, s1);
  basic_layer(sr, si, wc[1], wsn[1]);
  apply_ry<8>(sr, si, c0, s0);
  apply_ry<4>(sr, si, c1, s1);
  apply_ry<2>(sr, si, c0, s0);
  apply_ry<1>(sr, si, c1, s1);
  basic_layer(sr, si, wc[2], wsn[2]);

  float p[16];
#pragma unroll
  for (int k = 0; k < 16; ++k) p[k] = fmaf(sr[k], sr[k], si[k] * si[k]);

  float a1[8], ev3 = 0.0f;
#pragma unroll
  for (int k = 0; k < 8; ++k) {
    a1[k] = p[2 * k] + p[2 * k + 1];
    ev3 += p[2 * k] - p[2 * k + 1];
  }
  float a2[4], ev2 = 0.0f;
#pragma unroll
  for (int k = 0; k < 4; ++k) {
    a2[k] = a1[2 * k] + a1[2 * k + 1];
    ev2 += a1[2 * k] - a1[2 * k + 1];
  }
  ev[1] = (a2[0] - a2[1]) + (a2[2] - a2[3]);
  ev[0] = (a2[0] + a2[1]) - (a2[2] + a2[3]);
  ev[2] = ev2;
  ev[3] = ev3;
}

// u(w) = [1, cos w, sin w, cos2w, sin2w, cos3w, sin3w, cos4w, sin4w]  (validated R3)
__device__ __forceinline__ void build_u(float w, float u[9]) {
  float c, s;
  __sincosf(w, &s, &c);
  u[0] = 1.0f;
  u[1] = c;            u[2] = s;
  u[3] = fmaf(c, c, -(s * s));
  u[4] = 2.0f * s * c;
  u[5] = fmaf(c, u[3], -(s * u[4]));
  u[6] = fmaf(s, u[3], c * u[4]);
  u[7] = fmaf(c, u[5], -(s * u[6]));
  u[8] = fmaf(s, u[5], c * u[6]);
}

// ---------------- single fat kernel (R5 body + R4 last-block finish) ----------------
__global__ __launch_bounds__(THREADS) void fused_kernel(const float* __restrict__ x,
                                                        const float* __restrict__ weights,
                                                        const float* __restrict__ dw,
                                                        const float* __restrict__ db,
                                                        float* __restrict__ out,
                                                        unsigned int* __restrict__ cnt,
                                                        float* __restrict__ slots) {
  __shared__ float E[4][81];
  __shared__ float fb[9][9];
  __shared__ float T[4][81];
  __shared__ float Csh[432];     // C[q][m][n12], n padded to 12
  __shared__ float wvmax[4][4];
  __shared__ float Msh[64];
  __shared__ int lastflag;

  const int tid = threadIdx.x;
  const int blk = blockIdx.x;
  const int b   = blk >> 5;    // 0..15
  const int pb  = blk & 31;    // 0..31
  const int ch   = tid & 7;
  const int grp  = tid >> 3;               // 0..31
  const int base = pb * 128 + grp * 4;     // first position of this thread

  // early x loads (prefetch under phase 1)
  const float* rowx = x + ((size_t)(b * NCH + ch) << 12);
  float vals[W + 1];
  {
    const int i0 = base - 1;               // only low edge underflows; max base+3 = 4095
#pragma unroll
    for (int v = 0; v < W + 1; ++v) {
      const int idx = i0 + v;
      vals[v] = (idx >= 0) ? rowx[idx] : 0.0f;
    }
  }
  float U[W + 1][9];
#pragma unroll
  for (int v = 0; v < W + 1; ++v) build_u(vals[v], U[v]);

  // ---- phase 1: per-block fit (two-stage projection, validated R5) ----
  const float alpha = 6.2831853071795864f / 9.0f;
  if (tid < 81) {
    const int j = tid / 9, k = tid - j * 9;
    float ev[4];
    sim_circuit(weights, alpha * (float)j, alpha * (float)k, ev);
#pragma unroll
    for (int q = 0; q < 4; ++q) E[q][tid] = ev[q];
    const int m = j, jj = k;
    if (m == 0) {
      fb[0][jj] = 1.0f;
    } else {
      const int t = (m + 1) >> 1;
      float sv, cv;
      __sincosf(alpha * (float)(jj * t), &sv, &cv);
      fb[m][jj] = (m & 1) ? cv : sv;
    }
  }
  __syncthreads();
  for (int t = tid; t < 324; t += THREADS) {
    const int q = t / 81, r = t - q * 81, j = r / 9, n = r - j * 9;
    float acc = 0.0f;
#pragma unroll
    for (int k = 0; k < 9; ++k) acc = fmaf(fb[n][k], E[q][j * 9 + k], acc);
    T[q][j * 9 + n] = acc;
  }
  __syncthreads();
  for (int t = tid; t < 432; t += THREADS) {
    const int q = t / 108, r = t - q * 108, m = r / 12, n = r - m * 12;
    float val = 0.0f;
    if (n < 9) {
      float acc = 0.0f;
#pragma unroll
      for (int j = 0; j < 9; ++j) acc = fmaf(fb[m][j], T[q][j * 9 + n], acc);
      const float dm = (m == 0) ? 9.0f : 4.5f;
      const float dn = (n == 0) ? 9.0f : 4.5f;
      val = acc / (dm * dn);
    }
    Csh[t] = val;
  }
  __syncthreads();

  // ---- phase 2: 4 windows/thread, ev = u(w0)^T C u(w1) (validated R5) ----
  float acc[4][W];
#pragma unroll
  for (int q = 0; q < 4; ++q)
#pragma unroll
    for (int w = 0; w < W; ++w) acc[q][w] = 0.0f;

#pragma unroll
  for (int q = 0; q < 4; ++q) {
#pragma unroll
    for (int m = 0; m < 9; ++m) {
      const float* rp = Csh + q * 108 + m * 12;
      const float4 A  = *(const float4*)(rp);
      const float4 Bv = *(const float4*)(rp + 4);
      const float  r8 = rp[8];
#pragma unroll
      for (int w = 0; w < W; ++w) {
        float d = A.x;                         // u1[0] = 1
        d = fmaf(A.y,  U[w + 1][1], d);
        d = fmaf(A.z,  U[w + 1][2], d);
        d = fmaf(A.w,  U[w + 1][3], d);
        d = fmaf(Bv.x, U[w + 1][4], d);
        d = fmaf(Bv.y, U[w + 1][5], d);
        d = fmaf(Bv.z, U[w + 1][6], d);
        d = fmaf(Bv.w, U[w + 1][7], d);
        d = fmaf(r8,   U[w + 1][8], d);
        acc[q][w] = fmaf(U[w][m], d, acc[q][w]);
      }
    }
  }

  // channel all-reduce (tid = grp*8 + ch)
#pragma unroll
  for (int mask = 1; mask < 8; mask <<= 1)
#pragma unroll
    for (int q = 0; q < 4; ++q)
#pragma unroll
      for (int w = 0; w < W; ++w) acc[q][w] += __shfl_xor(acc[q][w], mask, 64);

  float mx[4] = {0.0f, 0.0f, 0.0f, 0.0f};
#pragma unroll
  for (int q = 0; q < 4; ++q)
#pragma unroll
    for (int w = 0; w < W; ++w) mx[q] = fmaxf(mx[q], acc[q][w]);

  // tail: pos 4096, window (x[4095], 0); u(0) = [1,1,0,1,0,1,0,1,0]
  if (pb == 31 && (tid >> 6) == 3) {       // wave-uniform; grp 24..31 in this wave
    float ev9[4];
#pragma unroll
    for (int q = 0; q < 4; ++q) {
      float s = 0.0f;
#pragma unroll
      for (int m = 0; m < 9; ++m) {
        const float* rp = Csh + q * 108 + m * 12;
        const float4 A  = *(const float4*)(rp);
        const float4 Bv = *(const float4*)(rp + 4);
        const float dt = A.x + A.y + A.w + Bv.y + Bv.w;   // n = 0,1,3,5,7
        s = fmaf(U[W][m], dt, s);
      }
      ev9[q] = (grp == 31) ? s : 0.0f;     // grp 31 holds x[4095] in vals[4]
    }
#pragma unroll
    for (int mask = 1; mask < 8; mask <<= 1)
#pragma unroll
      for (int q = 0; q < 4; ++q) ev9[q] += __shfl_xor(ev9[q], mask, 64);
#pragma unroll
    for (int q = 0; q < 4; ++q) mx[q] = fmaxf(mx[q], ev9[q]);
  }

  // position-group all-reduce within wave
#pragma unroll
  for (int mask = 8; mask < 64; mask <<= 1)
#pragma unroll
    for (int q = 0; q < 4; ++q) mx[q] = fmaxf(mx[q], __shfl_xor(mx[q], mask, 64));

  const int wv = tid >> 6;
  if ((tid & 63) == 0) {
#pragma unroll
    for (int q = 0; q < 4; ++q) wvmax[wv][q] = mx[q];
  }
  __syncthreads();
  if (tid < 4) {
    const float m01 = fmaxf(wvmax[0][tid], wvmax[1][tid]);
    const float m23 = fmaxf(wvmax[2][tid], wvmax[3][tid]);
    slots[blk * 4 + tid] = fmaxf(m01, m23);
  }
  __threadfence();                         // writer-side device-scope fence (R4-validated)
  __syncthreads();
  if (tid == 0) {
    const unsigned int old = atomicAdd(cnt, 1u);
    lastflag = (old == NBLK - 1) ? 1 : 0;
  }
  __syncthreads();

  // ---- phase 3: last block to finish reduces slots + dense ----
  if (lastflag) {                          // block-uniform; no spin -> no deadlock possible
    __threadfence();
    if (tid < 64) {
      const int bb = tid >> 2, q = tid & 3;
      float m = 0.0f;
#pragma unroll
      for (int p = 0; p < 32; ++p) m = fmaxf(m, slots[((bb << 5) + p) * 4 + q]);
      Msh[tid] = m;
    }
    __syncthreads();
    if (tid < NBS * 10) {
      const int bb = tid / 10, f = tid - bb * 10;
      float a2 = db[f];
#pragma unroll
      for (int q = 0; q < 4; ++q) a2 = fmaf(Msh[bb * 4 + q], dw[q * 10 + f], a2);
      out[tid] = a2;
    }
  }
}

extern "C" void kernel_launch(void* const* d_in, const int* in_sizes, int n_in,
                              void* d_out, int out_size, void* d_ws, size_t ws_size,
                              hipStream_t stream) {
  const float* x       = (const float*)d_in[0];  // (16, 8, 4096) f32
  const float* weights = (const float*)d_in[1];  // (3, 4) f32
  const float* dw      = (const float*)d_in[2];  // (4, 10) f32
  const float* db      = (const float*)d_in[3];  // (10,) f32
  float* out = (float*)d_out;                    // (16, 10) f32

  unsigned int* cnt = (unsigned int*)d_ws;
  float* slots = (float*)((char*)d_ws + 256);

  hipMemsetAsync(cnt, 0, sizeof(unsigned int), stream);
  fused_kernel<<<NBLK, THREADS, 0, stream>>>(x, weights, dw, db, out, cnt, slots);
}

// Round 12
// 32.239 us; speedup vs baseline: 1.8010x; 1.8010x over previous
//
#include <hip/hip_runtime.h>

// Problem constants
#define LIN   4096
#define NCH   8
#define NBS   16
#define THREADS 256
#define NBLK  512           // 16 b x 32 pb; 128 positions/block (R5 geometry, 2 blocks/CU)
#define W     4             // windows per thread
// d_ws layout (bytes), zeroed by ONE in-graph hipMemsetAsync(512B) each replay:
//  [0..3]     cnt (uint)
//  [256..511] Mu[16][4] (uint-as-float atomicMax targets; relu'd values >= 0)

// ---------------- register statevector sim (validated R0/R3/R5/R7/R8/R10: absmax 0.0) ----------------
template<int BIT>
__device__ __forceinline__ void apply_rx(float sr[16], float si[16], float c, float s) {
#pragma unroll
  for (int k = 0; k < 16; ++k) {
    if ((k & BIT) == 0) {
      const int a = k, b = k | BIT;
      const float ar = sr[a], ai = si[a], br = sr[b], bi = si[b];
      sr[a] = c * ar + s * bi;
      si[a] = c * ai - s * br;
      sr[b] = c * br + s * ai;
      si[b] = c * bi - s * ar;
    }
  }
}

template<int BIT>
__device__ __forceinline__ void apply_ry(float sr[16], float si[16], float c, float s) {
#pragma unroll
  for (int k = 0; k < 16; ++k) {
    if ((k & BIT) == 0) {
      const int a = k, b = k | BIT;
      const float ar = sr[a], ai = si[a], br = sr[b], bi = si[b];
      sr[a] = c * ar - s * br;
      si[a] = c * ai - s * bi;
      sr[b] = s * ar + c * br;
      si[b] = s * ai + c * bi;
    }
  }
}

template<int CBIT, int TBIT>
__device__ __forceinline__ void apply_cnot(float sr[16], float si[16]) {
#pragma unroll
  for (int k = 0; k < 16; ++k) {
    if ((k & CBIT) != 0 && (k & TBIT) == 0) {
      const int a = k, b = k | TBIT;
      float t;
      t = sr[a]; sr[a] = sr[b]; sr[b] = t;
      t = si[a]; si[a] = si[b]; si[b] = t;
    }
  }
}

__device__ __forceinline__ void basic_layer(float sr[16], float si[16],
                                            const float c[4], const float s[4]) {
  apply_rx<8>(sr, si, c[0], s[0]);
  apply_rx<4>(sr, si, c[1], s[1]);
  apply_rx<2>(sr, si, c[2], s[2]);
  apply_rx<1>(sr, si, c[3], s[3]);
  apply_cnot<8, 4>(sr, si);
  apply_cnot<4, 2>(sr, si);
  apply_cnot<2, 1>(sr, si);
  apply_cnot<1, 8>(sr, si);
}

__device__ void sim_circuit(const float* __restrict__ weights, float w0, float w1, float ev[4]) {
  float wc[3][4], wsn[3][4];
#pragma unroll
  for (int l = 0; l < 3; ++l)
#pragma unroll
    for (int q = 0; q < 4; ++q)
      __sincosf(weights[l * 4 + q] * 0.5f, &wsn[l][q], &wc[l][q]);

  float c0, s0, c1, s1;
  __sincosf(w0 * 0.5f, &s0, &c0);
  __sincosf(w1 * 0.5f, &s1, &c1);

  float sr[16], si[16];
#pragma unroll
  for (int k = 0; k < 16; ++k) { sr[k] = 0.0f; si[k] = 0.0f; }
  sr[0] = 1.0f;

  basic_layer(sr, si, wc[0], wsn[0]);
  apply_ry<8>(sr, si, c0, s0);
  apply_ry<4>(sr, si, c1, s1);
  apply_ry<2>(sr, si, c0, s0);
  apply_ry<1>(sr, si, c1, s1);
  basic_layer(sr, si, wc[1], wsn[1]);
  apply_ry<8>(sr, si, c0, s0);
  apply_ry<4>(sr, si, c1, s1);
  apply_ry<2>(sr, si, c0, s0);
  apply_ry<1>(sr, si, c1, s1);
  basic_layer(sr, si, wc[2], wsn[2]);

  float p[16];
#pragma unroll
  for (int k = 0; k < 16; ++k) p[k] = fmaf(sr[k], sr[k], si[k] * si[k]);

  float a1[8], ev3 = 0.0f;
#pragma unroll
  for (int k = 0; k < 8; ++k) {
    a1[k] = p[2 * k] + p[2 * k + 1];
    ev3 += p[2 * k] - p[2 * k + 1];
  }
  float a2[4], ev2 = 0.0f;
#pragma unroll
  for (int k = 0; k < 4; ++k) {
    a2[k] = a1[2 * k] + a1[2 * k + 1];
    ev2 += a1[2 * k] - a1[2 * k + 1];
  }
  ev[1] = (a2[0] - a2[1]) + (a2[2] - a2[3]);
  ev[0] = (a2[0] + a2[1]) - (a2[2] + a2[3]);
  ev[2] = ev2;
  ev[3] = ev3;
}

// u(w) = [1, cos w, sin w, cos2w, sin2w, cos3w, sin3w, cos4w, sin4w]  (validated R3)
__device__ __forceinline__ void build_u(float w, float u[9]) {
  float c, s;
  __sincosf(w, &s, &c);
  u[0] = 1.0f;
  u[1] = c;            u[2] = s;
  u[3] = fmaf(c, c, -(s * s));
  u[4] = 2.0f * s * c;
  u[5] = fmaf(c, u[3], -(s * u[4]));
  u[6] = fmaf(s, u[3], c * u[4]);
  u[7] = fmaf(c, u[5], -(s * u[6]));
  u[8] = fmaf(s, u[5], c * u[6]);
}

// ---------------- single fat kernel: R5 body + all-atomic fence-free finish ----------------
__global__ __launch_bounds__(THREADS) void fused_kernel(const float* __restrict__ x,
                                                        const float* __restrict__ weights,
                                                        const float* __restrict__ dw,
                                                        const float* __restrict__ db,
                                                        float* __restrict__ out,
                                                        unsigned int* __restrict__ cnt,
                                                        unsigned int* __restrict__ Mu) {
  __shared__ float E[4][81];
  __shared__ float fb[9][9];
  __shared__ float T[4][81];
  __shared__ float Csh[432];     // C[q][m][n12], n padded to 12
  __shared__ float wvmax[4][4];
  __shared__ float Msh[64];
  __shared__ int lastflag;

  const int tid = threadIdx.x;
  const int blk = blockIdx.x;
  const int b   = blk >> 5;    // 0..15
  const int pb  = blk & 31;    // 0..31
  const int ch   = tid & 7;
  const int grp  = tid >> 3;               // 0..31
  const int base = pb * 128 + grp * 4;     // first position of this thread

  // early x loads (prefetch under phase 1)
  const float* rowx = x + ((size_t)(b * NCH + ch) << 12);
  float vals[W + 1];
  {
    const int i0 = base - 1;               // only low edge underflows; max base+3 = 4095
#pragma unroll
    for (int v = 0; v < W + 1; ++v) {
      const int idx = i0 + v;
      vals[v] = (idx >= 0) ? rowx[idx] : 0.0f;
    }
  }
  float U[W + 1][9];
#pragma unroll
  for (int v = 0; v < W + 1; ++v) build_u(vals[v], U[v]);

  // ---- phase 1: per-block fit (two-stage projection, validated R5) ----
  const float alpha = 6.2831853071795864f / 9.0f;
  if (tid < 81) {
    const int j = tid / 9, k = tid - j * 9;
    float ev[4];
    sim_circuit(weights, alpha * (float)j, alpha * (float)k, ev);
#pragma unroll
    for (int q = 0; q < 4; ++q) E[q][tid] = ev[q];
    const int m = j, jj = k;
    if (m == 0) {
      fb[0][jj] = 1.0f;
    } else {
      const int t = (m + 1) >> 1;
      float sv, cv;
      __sincosf(alpha * (float)(jj * t), &sv, &cv);
      fb[m][jj] = (m & 1) ? cv : sv;
    }
  }
  __syncthreads();
  for (int t = tid; t < 324; t += THREADS) {
    const int q = t / 81, r = t - q * 81, j = r / 9, n = r - j * 9;
    float acc = 0.0f;
#pragma unroll
    for (int k = 0; k < 9; ++k) acc = fmaf(fb[n][k], E[q][j * 9 + k], acc);
    T[q][j * 9 + n] = acc;
  }
  __syncthreads();
  for (int t = tid; t < 432; t += THREADS) {
    const int q = t / 108, r = t - q * 108, m = r / 12, n = r - m * 12;
    float val = 0.0f;
    if (n < 9) {
      float acc = 0.0f;
#pragma unroll
      for (int j = 0; j < 9; ++j) acc = fmaf(fb[m][j], T[q][j * 9 + n], acc);
      const float dm = (m == 0) ? 9.0f : 4.5f;
      const float dn = (n == 0) ? 9.0f : 4.5f;
      val = acc / (dm * dn);
    }
    Csh[t] = val;
  }
  __syncthreads();

  // ---- phase 2: 4 windows/thread, ev = u(w0)^T C u(w1) (validated R5) ----
  float acc[4][W];
#pragma unroll
  for (int q = 0; q < 4; ++q)
#pragma unroll
    for (int w = 0; w < W; ++w) acc[q][w] = 0.0f;

#pragma unroll
  for (int q = 0; q < 4; ++q) {
#pragma unroll
    for (int m = 0; m < 9; ++m) {
      const float* rp = Csh + q * 108 + m * 12;
      const float4 A  = *(const float4*)(rp);
      const float4 Bv = *(const float4*)(rp + 4);
      const float  r8 = rp[8];
#pragma unroll
      for (int w = 0; w < W; ++w) {
        float d = A.x;                         // u1[0] = 1
        d = fmaf(A.y,  U[w + 1][1], d);
        d = fmaf(A.z,  U[w + 1][2], d);
        d = fmaf(A.w,  U[w + 1][3], d);
        d = fmaf(Bv.x, U[w + 1][4], d);
        d = fmaf(Bv.y, U[w + 1][5], d);
        d = fmaf(Bv.z, U[w + 1][6], d);
        d = fmaf(Bv.w, U[w + 1][7], d);
        d = fmaf(r8,   U[w + 1][8], d);
        acc[q][w] = fmaf(U[w][m], d, acc[q][w]);
      }
    }
  }

  // channel all-reduce (tid = grp*8 + ch)
#pragma unroll
  for (int mask = 1; mask < 8; mask <<= 1)
#pragma unroll
    for (int q = 0; q < 4; ++q)
#pragma unroll
      for (int w = 0; w < W; ++w) acc[q][w] += __shfl_xor(acc[q][w], mask, 64);

  float mx[4] = {0.0f, 0.0f, 0.0f, 0.0f};
#pragma unroll
  for (int q = 0; q < 4; ++q)
#pragma unroll
    for (int w = 0; w < W; ++w) mx[q] = fmaxf(mx[q], acc[q][w]);

  // tail: pos 4096, window (x[4095], 0); u(0) = [1,1,0,1,0,1,0,1,0]
  if (pb == 31 && (tid >> 6) == 3) {       // wave-uniform; grp 24..31 in this wave
    float ev9[4];
#pragma unroll
    for (int q = 0; q < 4; ++q) {
      float s = 0.0f;
#pragma unroll
      for (int m = 0; m < 9; ++m) {
        const float* rp = Csh + q * 108 + m * 12;
        const float4 A  = *(const float4*)(rp);
        const float4 Bv = *(const float4*)(rp + 4);
        const float dt = A.x + A.y + A.w + Bv.y + Bv.w;   // n = 0,1,3,5,7
        s = fmaf(U[W][m], dt, s);
      }
      ev9[q] = (grp == 31) ? s : 0.0f;     // grp 31 holds x[4095] in vals[4]
    }
#pragma unroll
    for (int mask = 1; mask < 8; mask <<= 1)
#pragma unroll
      for (int q = 0; q < 4; ++q) ev9[q] += __shfl_xor(ev9[q], mask, 64);
#pragma unroll
    for (int q = 0; q < 4; ++q) mx[q] = fmaxf(mx[q], ev9[q]);
  }

  // position-group all-reduce within wave
#pragma unroll
  for (int mask = 8; mask < 64; mask <<= 1)
#pragma unroll
    for (int q = 0; q < 4; ++q) mx[q] = fmaxf(mx[q], __shfl_xor(mx[q], mask, 64));

  const int wv = tid >> 6;
  if ((tid & 63) == 0) {
#pragma unroll
    for (int q = 0; q < 4; ++q) wvmax[wv][q] = mx[q];
  }
  __syncthreads();

  // ---- fence-free finish: device-scope atomics only ----
  if (tid < 4) {
    const float m01 = fmaxf(wvmax[0][tid], wvmax[1][tid]);
    const float m23 = fmaxf(wvmax[2][tid], wvmax[3][tid]);
    atomicMax(&Mu[b * 4 + tid], __float_as_uint(fmaxf(m01, m23)));   // coherent RMW
  }
  // drain outstanding vmem (atomicMax reaches the coherent point) before signaling
  asm volatile("s_waitcnt vmcnt(0)" ::: "memory");
  __syncthreads();
  if (tid == 0) {
    const unsigned int old = atomicAdd(cnt, 1u);
    lastflag = (old == NBLK - 1) ? 1 : 0;
  }
  __syncthreads();

  if (lastflag) {                          // exactly one block; no spin, no fence
    if (tid < 64) {
      const unsigned int u = atomicMax(&Mu[tid], 0u);   // coherent read of final max
      Msh[tid] = __uint_as_float(u);
    }
    __syncthreads();
    if (tid < NBS * 10) {
      const int bb = tid / 10, f = tid - bb * 10;
      float a2 = db[f];
#pragma unroll
      for (int q = 0; q < 4; ++q) a2 = fmaf(Msh[bb * 4 + q], dw[q * 10 + f], a2);
      out[tid] = a2;
    }
  }
}

extern "C" void kernel_launch(void* const* d_in, const int* in_sizes, int n_in,
                              void* d_out, int out_size, void* d_ws, size_t ws_size,
                              hipStream_t stream) {
  const float* x       = (const float*)d_in[0];  // (16, 8, 4096) f32
  const float* weights = (const float*)d_in[1];  // (3, 4) f32
  const float* dw      = (const float*)d_in[2];  // (4, 10) f32
  const float* db      = (const float*)d_in[3];  // (10,) f32
  float* out = (float*)d_out;                    // (16, 10) f32

  unsigned int* cnt = (unsigned int*)d_ws;                 // [0..3]
  unsigned int* Mu  = (unsigned int*)((char*)d_ws + 256);  // [256..511]

  hipMemsetAsync(d_ws, 0, 512, stream);   // zeroes cnt + Mu in one SDMA node
  fused_kernel<<<NBLK, THREADS, 0, stream>>>(x, weights, dw, db, out, cnt, Mu);
}

// Round 13
// 31.093 us; speedup vs baseline: 1.8673x; 1.0368x over previous
//
#include <hip/hip_runtime.h>

// Problem constants
#define LIN   4096
#define NCH   8
#define NBS   16
#define THREADS 256
#define NBLK  1024          // 16 b x 64 pb; 64 positions/block; 4 blocks/CU
#define W     2             // windows per thread
// d_ws float layout:
//  [0]        cnt (uint) — zeroed by fit_kernel (node 1) each call
//  [64..127]  Mu[16][4] — uint-as-float atomicMax targets, zeroed by fit_kernel
//  [128..559] C[4][9][12] (n padded to 12)

// ---------------- register statevector sim (validated R0/R3/R5/R10/R12: absmax 0.0) ----------------
template<int BIT>
__device__ __forceinline__ void apply_rx(float sr[16], float si[16], float c, float s) {
#pragma unroll
  for (int k = 0; k < 16; ++k) {
    if ((k & BIT) == 0) {
      const int a = k, b = k | BIT;
      const float ar = sr[a], ai = si[a], br = sr[b], bi = si[b];
      sr[a] = c * ar + s * bi;
      si[a] = c * ai - s * br;
      sr[b] = c * br + s * ai;
      si[b] = c * bi - s * ar;
    }
  }
}

template<int BIT>
__device__ __forceinline__ void apply_ry(float sr[16], float si[16], float c, float s) {
#pragma unroll
  for (int k = 0; k < 16; ++k) {
    if ((k & BIT) == 0) {
      const int a = k, b = k | BIT;
      const float ar = sr[a], ai = si[a], br = sr[b], bi = si[b];
      sr[a] = c * ar - s * br;
      si[a] = c * ai - s * bi;
      sr[b] = s * ar + c * br;
      si[b] = s * ai + c * bi;
    }
  }
}

template<int CBIT, int TBIT>
__device__ __forceinline__ void apply_cnot(float sr[16], float si[16]) {
#pragma unroll
  for (int k = 0; k < 16; ++k) {
    if ((k & CBIT) != 0 && (k & TBIT) == 0) {
      const int a = k, b = k | TBIT;
      float t;
      t = sr[a]; sr[a] = sr[b]; sr[b] = t;
      t = si[a]; si[a] = si[b]; si[b] = t;
    }
  }
}

__device__ __forceinline__ void basic_layer(float sr[16], float si[16],
                                            const float c[4], const float s[4]) {
  apply_rx<8>(sr, si, c[0], s[0]);
  apply_rx<4>(sr, si, c[1], s[1]);
  apply_rx<2>(sr, si, c[2], s[2]);
  apply_rx<1>(sr, si, c[3], s[3]);
  apply_cnot<8, 4>(sr, si);
  apply_cnot<4, 2>(sr, si);
  apply_cnot<2, 1>(sr, si);
  apply_cnot<1, 8>(sr, si);
}

__device__ void sim_circuit(const float* __restrict__ weights, float w0, float w1, float ev[4]) {
  float wc[3][4], wsn[3][4];
#pragma unroll
  for (int l = 0; l < 3; ++l)
#pragma unroll
    for (int q = 0; q < 4; ++q)
      __sincosf(weights[l * 4 + q] * 0.5f, &wsn[l][q], &wc[l][q]);

  float c0, s0, c1, s1;
  __sincosf(w0 * 0.5f, &s0, &c0);
  __sincosf(w1 * 0.5f, &s1, &c1);

  float sr[16], si[16];
#pragma unroll
  for (int k = 0; k < 16; ++k) { sr[k] = 0.0f; si[k] = 0.0f; }
  sr[0] = 1.0f;

  basic_layer(sr, si, wc[0], wsn[0]);
  apply_ry<8>(sr, si, c0, s0);
  apply_ry<4>(sr, si, c1, s1);
  apply_ry<2>(sr, si, c0, s0);
  apply_ry<1>(sr, si, c1, s1);
  basic_layer(sr, si, wc[1], wsn[1]);
  apply_ry<8>(sr, si, c0, s0);
  apply_ry<4>(sr, si, c1, s1);
  apply_ry<2>(sr, si, c0, s0);
  apply_ry<1>(sr, si, c1, s1);
  basic_layer(sr, si, wc[2], wsn[2]);

  float p[16];
#pragma unroll
  for (int k = 0; k < 16; ++k) p[k] = fmaf(sr[k], sr[k], si[k] * si[k]);

  float a1[8], ev3 = 0.0f;
#pragma unroll
  for (int k = 0; k < 8; ++k) {
    a1[k] = p[2 * k] + p[2 * k + 1];
    ev3 += p[2 * k] - p[2 * k + 1];
  }
  float a2[4], ev2 = 0.0f;
#pragma unroll
  for (int k = 0; k < 4; ++k) {
    a2[k] = a1[2 * k] + a1[2 * k + 1];
    ev2 += a1[2 * k] - a1[2 * k + 1];
  }
  ev[1] = (a2[0] - a2[1]) + (a2[2] - a2[3]);
  ev[0] = (a2[0] + a2[1]) - (a2[2] + a2[3]);
  ev[2] = ev2;
  ev[3] = ev3;
}

// u(w) = [1, cos w, sin w, cos2w, sin2w, cos3w, sin3w, cos4w, sin4w]  (validated R3)
__device__ __forceinline__ void build_u(float w, float u[9]) {
  float c, s;
  __sincosf(w, &s, &c);
  u[0] = 1.0f;
  u[1] = c;            u[2] = s;
  u[3] = fmaf(c, c, -(s * s));
  u[4] = 2.0f * s * c;
  u[5] = fmaf(c, u[3], -(s * u[4]));
  u[6] = fmaf(s, u[3], c * u[4]);
  u[7] = fmaf(c, u[5], -(s * u[6]));
  u[8] = fmaf(s, u[5], c * u[6]);
}

// ---------------- node 1: one block fits C -> GLOBAL ws, zeroes cnt + Mu (R10-validated) ----------------
__global__ __launch_bounds__(THREADS) void fit_kernel(const float* __restrict__ weights,
                                                      float* __restrict__ wsf) {
  __shared__ float E[4][81];
  __shared__ float fbv[9][9];
  __shared__ float T[4][81];
  const int tid = threadIdx.x;
  if (tid == 0) ((unsigned int*)wsf)[0] = 0u;     // cnt
  if (tid < 64) wsf[64 + tid] = 0.0f;             // Mu atomic-max targets

  const float alpha = 6.2831853071795864f / 9.0f;
  if (tid < 81) {
    const int j = tid / 9, k = tid - j * 9;
    float ev[4];
    sim_circuit(weights, alpha * (float)j, alpha * (float)k, ev);
#pragma unroll
    for (int q = 0; q < 4; ++q) E[q][tid] = ev[q];
    const int m = j, jj = k;
    if (m == 0) {
      fbv[0][jj] = 1.0f;
    } else {
      const int t = (m + 1) >> 1;
      float sv, cv;
      __sincosf(alpha * (float)(jj * t), &sv, &cv);
      fbv[m][jj] = (m & 1) ? cv : sv;
    }
  }
  __syncthreads();
  for (int t = tid; t < 324; t += THREADS) {
    const int q = t / 81, r = t - q * 81, j = r / 9, n = r - j * 9;
    float acc = 0.0f;
#pragma unroll
    for (int k = 0; k < 9; ++k) acc = fmaf(fbv[n][k], E[q][j * 9 + k], acc);
    T[q][j * 9 + n] = acc;
  }
  __syncthreads();
  for (int t = tid; t < 432; t += THREADS) {
    const int q = t / 108, r = t - q * 108, m = r / 12, n = r - m * 12;
    float val = 0.0f;
    if (n < 9) {
      float acc = 0.0f;
#pragma unroll
      for (int j = 0; j < 9; ++j) acc = fmaf(fbv[m][j], T[q][j * 9 + n], acc);
      const float dm = (m == 0) ? 9.0f : 4.5f;
      const float dn = (n == 0) ? 9.0f : 4.5f;
      val = acc / (dm * dn);
    }
    wsf[128 + t] = val;
  }
}

// ---------------- node 2: stage C -> LDS, 2 windows/thread, atomic finish + dense ----------------
__global__ __launch_bounds__(THREADS) void main_kernel(const float* __restrict__ x,
                                                       const float* __restrict__ dw,
                                                       const float* __restrict__ db,
                                                       float* __restrict__ out,
                                                       float* __restrict__ wsf) {
  __shared__ float Csh[432];     // C[q][m][n12]
  __shared__ float wvmax[4][4];
  __shared__ float Msh[64];
  __shared__ int lastflag;

  const int tid = threadIdx.x;
  const int blk = blockIdx.x;
  const int b   = blk >> 6;                // 0..15
  const int pb  = blk & 63;                // 0..63
  const int ch  = tid & 7;
  const int grp = tid >> 3;                // 0..31
  const int base = pb * 64 + grp * W;      // first position of this thread

  unsigned int* cnt = (unsigned int*)wsf;
  unsigned int* Mu  = (unsigned int*)(wsf + 64);

  // stage C global -> LDS (block-wide, 432 floats; L2-resident after first block)
  for (int t = tid; t < 432; t += THREADS) Csh[t] = wsf[128 + t];

  // x window values (overlap staging latency)
  const float* rowx = x + ((size_t)(b * NCH + ch) << 12);
  float vals[W + 1];
  {
    const int i0 = base - 1;               // max idx = base+1 <= 4095; only low edge underflows
#pragma unroll
    for (int v = 0; v < W + 1; ++v) {
      const int idx = i0 + v;
      vals[v] = (idx >= 0) ? rowx[idx] : 0.0f;
    }
  }
  float U[W + 1][9];
#pragma unroll
  for (int v = 0; v < W + 1; ++v) build_u(vals[v], U[v]);

  __syncthreads();                         // Csh ready

  // phase 2: ev = u(w0)^T C u(w1) per window (validated R5 inner loop)
  float acc[4][W];
#pragma unroll
  for (int q = 0; q < 4; ++q)
#pragma unroll
    for (int w = 0; w < W; ++w) acc[q][w] = 0.0f;

#pragma unroll
  for (int q = 0; q < 4; ++q) {
#pragma unroll
    for (int m = 0; m < 9; ++m) {
      const float* rp = Csh + q * 108 + m * 12;
      const float4 A  = *(const float4*)(rp);
      const float4 Bv = *(const float4*)(rp + 4);
      const float  r8 = rp[8];
#pragma unroll
      for (int w = 0; w < W; ++w) {
        float d = A.x;                     // u1[0] = 1
        d = fmaf(A.y,  U[w + 1][1], d);
        d = fmaf(A.z,  U[w + 1][2], d);
        d = fmaf(A.w,  U[w + 1][3], d);
        d = fmaf(Bv.x, U[w + 1][4], d);
        d = fmaf(Bv.y, U[w + 1][5], d);
        d = fmaf(Bv.z, U[w + 1][6], d);
        d = fmaf(Bv.w, U[w + 1][7], d);
        d = fmaf(r8,   U[w + 1][8], d);
        acc[q][w] = fmaf(U[w][m], d, acc[q][w]);
      }
    }
  }

  // channel all-reduce (tid = grp*8 + ch)
#pragma unroll
  for (int mask = 1; mask < 8; mask <<= 1)
#pragma unroll
    for (int q = 0; q < 4; ++q)
#pragma unroll
      for (int w = 0; w < W; ++w) acc[q][w] += __shfl_xor(acc[q][w], mask, 64);

  float mx[4] = {0.0f, 0.0f, 0.0f, 0.0f};
#pragma unroll
  for (int q = 0; q < 4; ++q)
#pragma unroll
    for (int w = 0; w < W; ++w) mx[q] = fmaxf(mx[q], acc[q][w]);

  // tail: pos 4096, window (x[4095], 0); u(0) = [1,1,0,1,0,1,0,1,0]
  if (pb == 63 && (tid >> 6) == 3) {       // wave-uniform; grps 24..31
    float ev9[4];
#pragma unroll
    for (int q = 0; q < 4; ++q) {
      float s = 0.0f;
#pragma unroll
      for (int m = 0; m < 9; ++m) {
        const float* rp = Csh + q * 108 + m * 12;
        const float dt = rp[0] + rp[1] + rp[3] + rp[5] + rp[7];   // n = 0,1,3,5,7
        s = fmaf(U[W][m], dt, s);
      }
      ev9[q] = (grp == 31) ? s : 0.0f;     // grp 31: vals[W] = x[4095]
    }
#pragma unroll
    for (int mask = 1; mask < 8; mask <<= 1)
#pragma unroll
      for (int q = 0; q < 4; ++q) ev9[q] += __shfl_xor(ev9[q], mask, 64);
#pragma unroll
    for (int q = 0; q < 4; ++q) mx[q] = fmaxf(mx[q], ev9[q]);
  }

  // position-group all-reduce within wave
#pragma unroll
  for (int mask = 8; mask < 64; mask <<= 1)
#pragma unroll
    for (int q = 0; q < 4; ++q) mx[q] = fmaxf(mx[q], __shfl_xor(mx[q], mask, 64));

  const int wv = tid >> 6;
  if ((tid & 63) == 0) {
#pragma unroll
    for (int q = 0; q < 4; ++q) wvmax[wv][q] = mx[q];
  }
  __syncthreads();

  // fence-free finish: device-scope atomics only (R12-validated)
  if (tid < 4) {
    const float m01 = fmaxf(wvmax[0][tid], wvmax[1][tid]);
    const float m23 = fmaxf(wvmax[2][tid], wvmax[3][tid]);
    atomicMax(&Mu[b * 4 + tid], __float_as_uint(fmaxf(m01, m23)));
  }
  __syncthreads();                         // compiler drains vmem before barrier
  if (tid == 0) {
    const unsigned int old = atomicAdd(cnt, 1u);
    lastflag = (old == NBLK - 1) ? 1 : 0;
  }
  __syncthreads();

  if (lastflag) {                          // exactly one block; no spin, no fence
    if (tid < 64) {
      const unsigned int u = atomicMax(&Mu[tid], 0u);   // coherent RMW read
      Msh[tid] = __uint_as_float(u);
    }
    __syncthreads();
    if (tid < NBS * 10) {
      const int bb = tid / 10, f = tid - bb * 10;
      float a2 = db[f];
#pragma unroll
      for (int q = 0; q < 4; ++q) a2 = fmaf(Msh[bb * 4 + q], dw[q * 10 + f], a2);
      out[tid] = a2;
    }
  }
}

extern "C" void kernel_launch(void* const* d_in, const int* in_sizes, int n_in,
                              void* d_out, int out_size, void* d_ws, size_t ws_size,
                              hipStream_t stream) {
  const float* x       = (const float*)d_in[0];  // (16, 8, 4096) f32
  const float* weights = (const float*)d_in[1];  // (3, 4) f32
  const float* dw      = (const float*)d_in[2];  // (4, 10) f32
  const float* db      = (const float*)d_in[3];  // (10,) f32
  float* out = (float*)d_out;                    // (16, 10) f32
  float* wsf = (float*)d_ws;

  fit_kernel<<<1, THREADS, 0, stream>>>(weights, wsf);
  main_kernel<<<NBLK, THREADS, 0, stream>>>(x, dw, db, out, wsf);
}

// Round 14
// 27.402 us; speedup vs baseline: 2.1189x; 1.1347x over previous
//
#include <hip/hip_runtime.h>

// Problem constants
#define LIN   4096
#define NCH   8
#define NBS   16
#define FTHREADS 256        // fit_kernel block size
#define MTHREADS 128        // main_kernel block size (16 grp x 8 ch)
#define NBLK  512           // 16 b x 32 pb; 128 positions/block; 2 blocks/CU
#define W     8             // windows per thread (LDS C-reads amortized 8x)
// d_ws float layout:
//  [0]        cnt (uint) — zeroed by fit_kernel (node 1) each call
//  [64..127]  Mu[16][4] — uint-as-float atomicMax targets, zeroed by fit_kernel
//  [128..559] C[4][9][12] (n padded to 12)

// ---------------- register statevector sim (validated R0/R3/R5/R10/R12/R13) ----------------
template<int BIT>
__device__ __forceinline__ void apply_rx(float sr[16], float si[16], float c, float s) {
#pragma unroll
  for (int k = 0; k < 16; ++k) {
    if ((k & BIT) == 0) {
      const int a = k, b = k | BIT;
      const float ar = sr[a], ai = si[a], br = sr[b], bi = si[b];
      sr[a] = c * ar + s * bi;
      si[a] = c * ai - s * br;
      sr[b] = c * br + s * ai;
      si[b] = c * bi - s * ar;
    }
  }
}

template<int BIT>
__device__ __forceinline__ void apply_ry(float sr[16], float si[16], float c, float s) {
#pragma unroll
  for (int k = 0; k < 16; ++k) {
    if ((k & BIT) == 0) {
      const int a = k, b = k | BIT;
      const float ar = sr[a], ai = si[a], br = sr[b], bi = si[b];
      sr[a] = c * ar - s * br;
      si[a] = c * ai - s * bi;
      sr[b] = s * ar + c * br;
      si[b] = s * ai + c * bi;
    }
  }
}

template<int CBIT, int TBIT>
__device__ __forceinline__ void apply_cnot(float sr[16], float si[16]) {
#pragma unroll
  for (int k = 0; k < 16; ++k) {
    if ((k & CBIT) != 0 && (k & TBIT) == 0) {
      const int a = k, b = k | TBIT;
      float t;
      t = sr[a]; sr[a] = sr[b]; sr[b] = t;
      t = si[a]; si[a] = si[b]; si[b] = t;
    }
  }
}

__device__ __forceinline__ void basic_layer(float sr[16], float si[16],
                                            const float c[4], const float s[4]) {
  apply_rx<8>(sr, si, c[0], s[0]);
  apply_rx<4>(sr, si, c[1], s[1]);
  apply_rx<2>(sr, si, c[2], s[2]);
  apply_rx<1>(sr, si, c[3], s[3]);
  apply_cnot<8, 4>(sr, si);
  apply_cnot<4, 2>(sr, si);
  apply_cnot<2, 1>(sr, si);
  apply_cnot<1, 8>(sr, si);
}

__device__ void sim_circuit(const float* __restrict__ weights, float w0, float w1, float ev[4]) {
  float wc[3][4], wsn[3][4];
#pragma unroll
  for (int l = 0; l < 3; ++l)
#pragma unroll
    for (int q = 0; q < 4; ++q)
      __sincosf(weights[l * 4 + q] * 0.5f, &wsn[l][q], &wc[l][q]);

  float c0, s0, c1, s1;
  __sincosf(w0 * 0.5f, &s0, &c0);
  __sincosf(w1 * 0.5f, &s1, &c1);

  float sr[16], si[16];
#pragma unroll
  for (int k = 0; k < 16; ++k) { sr[k] = 0.0f; si[k] = 0.0f; }
  sr[0] = 1.0f;

  basic_layer(sr, si, wc[0], wsn[0]);
  apply_ry<8>(sr, si, c0, s0);
  apply_ry<4>(sr, si, c1, s1);
  apply_ry<2>(sr, si, c0, s0);
  apply_ry<1>(sr, si, c1, s1);
  basic_layer(sr, si, wc[1], wsn[1]);
  apply_ry<8>(sr, si, c0, s0);
  apply_ry<4>(sr, si, c1, s1);
  apply_ry<2>(sr, si, c0, s0);
  apply_ry<1>(sr, si, c1, s1);
  basic_layer(sr, si, wc[2], wsn[2]);

  float p[16];
#pragma unroll
  for (int k = 0; k < 16; ++k) p[k] = fmaf(sr[k], sr[k], si[k] * si[k]);

  float a1[8], ev3 = 0.0f;
#pragma unroll
  for (int k = 0; k < 8; ++k) {
    a1[k] = p[2 * k] + p[2 * k + 1];
    ev3 += p[2 * k] - p[2 * k + 1];
  }
  float a2[4], ev2 = 0.0f;
#pragma unroll
  for (int k = 0; k < 4; ++k) {
    a2[k] = a1[2 * k] + a1[2 * k + 1];
    ev2 += a1[2 * k] - a1[2 * k + 1];
  }
  ev[1] = (a2[0] - a2[1]) + (a2[2] - a2[3]);
  ev[0] = (a2[0] + a2[1]) - (a2[2] + a2[3]);
  ev[2] = ev2;
  ev[3] = ev3;
}

// u(w) = [1, cos w, sin w, cos2w, sin2w, cos3w, sin3w, cos4w, sin4w]  (validated R3)
__device__ __forceinline__ void build_u(float w, float u[9]) {
  float c, s;
  __sincosf(w, &s, &c);
  u[0] = 1.0f;
  u[1] = c;            u[2] = s;
  u[3] = fmaf(c, c, -(s * s));
  u[4] = 2.0f * s * c;
  u[5] = fmaf(c, u[3], -(s * u[4]));
  u[6] = fmaf(s, u[3], c * u[4]);
  u[7] = fmaf(c, u[5], -(s * u[6]));
  u[8] = fmaf(s, u[5], c * u[6]);
}

// ---------------- node 1: one block fits C -> GLOBAL ws, zeroes cnt + Mu (R13-validated) ----------------
__global__ __launch_bounds__(FTHREADS) void fit_kernel(const float* __restrict__ weights,
                                                       float* __restrict__ wsf) {
  __shared__ float E[4][81];
  __shared__ float fbv[9][9];
  __shared__ float T[4][81];
  const int tid = threadIdx.x;
  if (tid == 0) ((unsigned int*)wsf)[0] = 0u;     // cnt
  if (tid < 64) wsf[64 + tid] = 0.0f;             // Mu atomic-max targets

  const float alpha = 6.2831853071795864f / 9.0f;
  if (tid < 81) {
    const int j = tid / 9, k = tid - j * 9;
    float ev[4];
    sim_circuit(weights, alpha * (float)j, alpha * (float)k, ev);
#pragma unroll
    for (int q = 0; q < 4; ++q) E[q][tid] = ev[q];
    const int m = j, jj = k;
    if (m == 0) {
      fbv[0][jj] = 1.0f;
    } else {
      const int t = (m + 1) >> 1;
      float sv, cv;
      __sincosf(alpha * (float)(jj * t), &sv, &cv);
      fbv[m][jj] = (m & 1) ? cv : sv;
    }
  }
  __syncthreads();
  for (int t = tid; t < 324; t += FTHREADS) {
    const int q = t / 81, r = t - q * 81, j = r / 9, n = r - j * 9;
    float acc = 0.0f;
#pragma unroll
    for (int k = 0; k < 9; ++k) acc = fmaf(fbv[n][k], E[q][j * 9 + k], acc);
    T[q][j * 9 + n] = acc;
  }
  __syncthreads();
  for (int t = tid; t < 432; t += FTHREADS) {
    const int q = t / 108, r = t - q * 108, m = r / 12, n = r - m * 12;
    float val = 0.0f;
    if (n < 9) {
      float acc = 0.0f;
#pragma unroll
      for (int j = 0; j < 9; ++j) acc = fmaf(fbv[m][j], T[q][j * 9 + n], acc);
      const float dm = (m == 0) ? 9.0f : 4.5f;
      const float dn = (n == 0) ? 9.0f : 4.5f;
      val = acc / (dm * dn);
    }
    wsf[128 + t] = val;
  }
}

// ---------------- node 2: W=8 windows/thread, staged C, atomic finish (R13 protocol) ----------------
__global__ __launch_bounds__(MTHREADS) void main_kernel(const float* __restrict__ x,
                                                        const float* __restrict__ dw,
                                                        const float* __restrict__ db,
                                                        float* __restrict__ out,
                                                        float* __restrict__ wsf) {
  __shared__ float Csh[432];     // C[q][m][n12]
  __shared__ float wvmax[2][4];
  __shared__ float Msh[64];
  __shared__ int lastflag;

  const int tid = threadIdx.x;
  const int blk = blockIdx.x;
  const int b   = blk >> 5;                // 0..15
  const int pb  = blk & 31;                // 0..31
  const int ch  = tid & 7;
  const int grp = tid >> 3;                // 0..15
  const int base = pb * 128 + grp * W;     // first position of this thread

  unsigned int* cnt = (unsigned int*)wsf;
  unsigned int* Mu  = (unsigned int*)(wsf + 64);

  // stage C global -> LDS (432 floats; L2-resident)
  for (int t = tid; t < 432; t += MTHREADS) Csh[t] = wsf[128 + t];

  // x window values (overlap staging latency)
  const float* rowx = x + ((size_t)(b * NCH + ch) << 12);
  float vals[W + 1];
  {
    const int i0 = base - 1;               // max idx = base+7 = 4095; only low edge underflows
#pragma unroll
    for (int v = 0; v < W + 1; ++v) {
      const int idx = i0 + v;
      vals[v] = (idx >= 0) ? rowx[idx] : 0.0f;
    }
  }
  float U[W + 1][9];
#pragma unroll
  for (int v = 0; v < W + 1; ++v) build_u(vals[v], U[v]);

  __syncthreads();                         // Csh ready

  // phase 2: ev = u(w0)^T C u(w1); 8-way w-ILP hides LDS latency
  float acc[4][W];
#pragma unroll
  for (int q = 0; q < 4; ++q)
#pragma unroll
    for (int w = 0; w < W; ++w) acc[q][w] = 0.0f;

#pragma unroll
  for (int q = 0; q < 4; ++q) {
#pragma unroll
    for (int m = 0; m < 9; ++m) {
      const float* rp = Csh + q * 108 + m * 12;
      const float4 A  = *(const float4*)(rp);
      const float4 Bv = *(const float4*)(rp + 4);
      const float  r8 = rp[8];
#pragma unroll
      for (int w = 0; w < W; ++w) {
        float d = A.x;                     // u1[0] = 1
        d = fmaf(A.y,  U[w + 1][1], d);
        d = fmaf(A.z,  U[w + 1][2], d);
        d = fmaf(A.w,  U[w + 1][3], d);
        d = fmaf(Bv.x, U[w + 1][4], d);
        d = fmaf(Bv.y, U[w + 1][5], d);
        d = fmaf(Bv.z, U[w + 1][6], d);
        d = fmaf(Bv.w, U[w + 1][7], d);
        d = fmaf(r8,   U[w + 1][8], d);
        acc[q][w] = fmaf(U[w][m], d, acc[q][w]);
      }
    }
  }

  // channel all-reduce (tid = grp*8 + ch)
#pragma unroll
  for (int mask = 1; mask < 8; mask <<= 1)
#pragma unroll
    for (int q = 0; q < 4; ++q)
#pragma unroll
      for (int w = 0; w < W; ++w) acc[q][w] += __shfl_xor(acc[q][w], mask, 64);

  float mx[4] = {0.0f, 0.0f, 0.0f, 0.0f};
#pragma unroll
  for (int q = 0; q < 4; ++q)
#pragma unroll
    for (int w = 0; w < W; ++w) mx[q] = fmaxf(mx[q], acc[q][w]);

  // tail: pos 4096, window (x[4095], 0); u(0) = [1,1,0,1,0,1,0,1,0]
  if (pb == 31 && (tid >> 6) == 1) {       // wave-uniform; wave 1 holds grp 8..15
    float ev9[4];
#pragma unroll
    for (int q = 0; q < 4; ++q) {
      float s = 0.0f;
#pragma unroll
      for (int m = 0; m < 9; ++m) {
        const float* rp = Csh + q * 108 + m * 12;
        const float dt = rp[0] + rp[1] + rp[3] + rp[5] + rp[7];   // n = 0,1,3,5,7
        s = fmaf(U[W][m], dt, s);
      }
      ev9[q] = (grp == 15) ? s : 0.0f;     // grp 15: vals[8] = x[4095]
    }
#pragma unroll
    for (int mask = 1; mask < 8; mask <<= 1)
#pragma unroll
      for (int q = 0; q < 4; ++q) ev9[q] += __shfl_xor(ev9[q], mask, 64);
#pragma unroll
    for (int q = 0; q < 4; ++q) mx[q] = fmaxf(mx[q], ev9[q]);
  }

  // position-group all-reduce within wave (grp bits 3..5 of lane)
#pragma unroll
  for (int mask = 8; mask < 64; mask <<= 1)
#pragma unroll
    for (int q = 0; q < 4; ++q) mx[q] = fmaxf(mx[q], __shfl_xor(mx[q], mask, 64));

  const int wv = tid >> 6;                 // 0..1
  if ((tid & 63) == 0) {
#pragma unroll
    for (int q = 0; q < 4; ++q) wvmax[wv][q] = mx[q];
  }
  __syncthreads();

  // fence-free finish: device-scope atomics only (R12/R13-validated)
  if (tid < 4) {
    atomicMax(&Mu[b * 4 + tid],
              __float_as_uint(fmaxf(wvmax[0][tid], wvmax[1][tid])));
  }
  __syncthreads();                         // compiler drains vmem before barrier
  if (tid == 0) {
    const unsigned int old = atomicAdd(cnt, 1u);
    lastflag = (old == NBLK - 1) ? 1 : 0;
  }
  __syncthreads();

  if (lastflag) {                          // exactly one block; no spin, no fence
    if (tid < 64) {
      const unsigned int u = atomicMax(&Mu[tid], 0u);   // coherent RMW read
      Msh[tid] = __uint_as_float(u);
    }
    __syncthreads();
    for (int t = tid; t < NBS * 10; t += MTHREADS) {
      const int bb = t / 10, f = t - bb * 10;
      float a2 = db[f];
#pragma unroll
      for (int q = 0; q < 4; ++q) a2 = fmaf(Msh[bb * 4 + q], dw[q * 10 + f], a2);
      out[t] = a2;
    }
  }
}

extern "C" void kernel_launch(void* const* d_in, const int* in_sizes, int n_in,
                              void* d_out, int out_size, void* d_ws, size_t ws_size,
                              hipStream_t stream) {
  const float* x       = (const float*)d_in[0];  // (16, 8, 4096) f32
  const float* weights = (const float*)d_in[1];  // (3, 4) f32
  const float* dw      = (const float*)d_in[2];  // (4, 10) f32
  const float* db      = (const float*)d_in[3];  // (10,) f32
  float* out = (float*)d_out;                    // (16, 10) f32
  float* wsf = (float*)d_ws;

  fit_kernel<<<1, FTHREADS, 0, stream>>>(weights, wsf);
  main_kernel<<<NBLK, MTHREADS, 0, stream>>>(x, dw, db, out, wsf);
}